// Round 6
// baseline (591.761 us; speedup 1.0000x reference)
//
#include <hip/hip_runtime.h>
#include <hip/hip_bf16.h>

#define B_ 32
#define T_ 4096
#define H_ 512
#define NEGV (-1000000000.0f)
#define LOG2E 1.4426950408889634f

using bf16x8  = __attribute__((ext_vector_type(8))) __bf16;
using short8  = __attribute__((ext_vector_type(8))) short;
using f32x4   = __attribute__((ext_vector_type(4))) float;

static __device__ __forceinline__ short f2bf(float f) {
    unsigned u = __builtin_bit_cast(unsigned, f);
    unsigned r = (u + 0x7fffu + ((u >> 16) & 1u)) >> 16;
    return (short)r;
}

static __device__ __forceinline__ float tanh_fast(float x) {
    float e = __builtin_amdgcn_exp2f(x * 2.8853900817779268f); // 2*log2(e)
    return 1.0f - 2.0f * __builtin_amdgcn_rcpf(e + 1.0f);
}

static __device__ __forceinline__ f32x4 mfma16(short8 a, short8 b, f32x4 c) {
    return __builtin_amdgcn_mfma_f32_16x16x32_bf16(
        __builtin_bit_cast(bf16x8, a), __builtin_bit_cast(bf16x8, b), c, 0, 0, 0);
}

// async global->LDS, 16B per lane; lds dest = uniform base + lane*16
#define GLOAD_LDS16(g, l)                                                     \
    __builtin_amdgcn_global_load_lds(                                         \
        (const __attribute__((address_space(1))) unsigned*)(g),               \
        (__attribute__((address_space(3))) unsigned*)(l), 16, 0, 0)

// ---------------------------------------------------------------------------
// Kernel 0: Wh fp32 -> bf16 in PIECE order for the k-outer e_fused.
// Piece P (8 KiB) = (h, q, nc): h = n-half (0..1), q = k-quarter (0..3),
// nc = n-chunk-of-32 within half (0..7).  P = h*32 + q*8 + nc.
// Within piece, slot idx = (s*4 + ks)*64 + l  (s: n-subgroup, ks: k-sub):
//   n = h*256 + nc*32 + s*16 + (l&15)
//   k = q*128 + ks*32 + (l>>4)*8 .. +7
// => e_fused stages pieces linearly and reads ds_read_b128 at
//    (uniform + lane*16): contiguous, conflict-free.
// grid 128, block 256 (one thread per 16B slot; 32768 slots).
__global__ __launch_bounds__(256) void wh_prep(const float* __restrict__ Wh,
                                               short* __restrict__ Whp) {
    int id = blockIdx.x * 256 + threadIdx.x;
    int P   = id >> 9;
    int idx = id & 511;
    int h  = P >> 5;
    int q  = (P >> 3) & 3;
    int nc = P & 7;
    int s  = idx >> 8;
    int ks = (idx >> 6) & 3;
    int l  = idx & 63;
    int n  = h * 256 + nc * 32 + s * 16 + (l & 15);
    int k0 = q * 128 + ks * 32 + (l >> 4) * 8;
    const float4* src = (const float4*)(Wh + (size_t)n * H_ + k0);
    float4 f0 = src[0];
    float4 f1 = src[1];
    short8 t;
    t[0] = f2bf(f0.x); t[1] = f2bf(f0.y); t[2] = f2bf(f0.z); t[3] = f2bf(f0.w);
    t[4] = f2bf(f1.x); t[5] = f2bf(f1.y); t[6] = f2bf(f1.z); t[7] = f2bf(f1.w);
    *(short8*)(Whp + (size_t)id * 8) = t;
}

// ---------------------------------------------------------------------------
// Kernel 1: s[b,o] = sum_k dec[b,k] * Ws[o,k]    (tiny)
__global__ __launch_bounds__(256) void s_kernel(const float* __restrict__ dec,
                                                const float* __restrict__ Ws,
                                                float* __restrict__ s_out) {
    __shared__ float dec_l[H_];
    int b = blockIdx.y;
    int tid = threadIdx.x;
    dec_l[tid]       = dec[b * H_ + tid];
    dec_l[tid + 256] = dec[b * H_ + tid + 256];
    __syncthreads();
    int o = blockIdx.x * 256 + tid;
    const float4* w = (const float4*)(Ws + (size_t)o * H_);
    float acc = 0.f;
#pragma unroll 8
    for (int k = 0; k < H_ / 4; ++k) {
        float4 wv = w[k];
        acc += wv.x * dec_l[4 * k] + wv.y * dec_l[4 * k + 1] +
               wv.z * dec_l[4 * k + 2] + wv.w * dec_l[4 * k + 3];
    }
    s_out[b * H_ + o] = acc;
}

// ---------------------------------------------------------------------------
// Kernel 2 (FUSED, k-outer / acc-stationary): per 64-row block:
//   h[t,n] accumulated over k-QUARTERS (A streamed, 16 regs/quarter) into
//   stationary acc regs (64/lane for a 256-n half); tanh+v-dot at quarter 3;
//   two n-halves sequentially (A read twice from HBM -- spread, overlapped).
// This removes the R5 structure's serial HBM prologue burst (was ~21 us per
// block generation, the dominant term) and keeps the live set ~145 regs so
// the allocator's hard 128-VGPR preference costs at most ~17 cold spills
// (measured R1/R5: 64 B/thread, benign) instead of afrag's in-loop spill.
// grid (B*T/64), block 256 (4 waves x 16 rows).
__global__ __launch_bounds__(256)
__attribute__((amdgpu_waves_per_eu(2, 2)))
void e_fused(const float* __restrict__ enc,
             const int* __restrict__ mask,
             const short* __restrict__ Whp,
             const float* __restrict__ s_in,
             const float* __restrict__ v,
             float* __restrict__ pctx,
             float* __restrict__ ml) {
    __shared__ short lds_b[2][8192];   // 2 x 16 KiB (2 pieces per buffer)
    __shared__ float s_l[H_];
    __shared__ float v_l[H_];
    __shared__ float e_l[64];

    const int tid  = threadIdx.x;
    const int wave = tid >> 6;
    const int lane = tid & 63;
    const int q4   = lane >> 4;   // k-octet 0..3
    const int lq   = lane & 15;

    const int row0 = blockIdx.x * 64;
    const int b    = row0 >> 12;   // / T_

    for (int i = tid; i < H_; i += 256) {
        s_l[i] = s_in[b * H_ + i];
        v_l[i] = v[i];
    }

    const int arow = row0 + wave * 16 + lq;
    const float* abase = enc + (size_t)arow * H_ + q4 * 8;

    // Stage step 0 (pieces 0,1 = 16 KiB): per wave 4 x 1 KiB.
    {
        const char* g = (const char*)Whp;
#pragma unroll
        for (int j = 0; j < 4; ++j) {
            int off = wave * 4096 + j * 1024;
            GLOAD_LDS16(g + off + lane * 16, (char*)lds_b[0] + off);
        }
    }

    // A quarter 0: load f32 + convert to bf16 fragments (16 regs).
    float4 fbuf[8];
#pragma unroll
    for (int ks = 0; ks < 4; ++ks) {
        fbuf[2 * ks]     = *(const float4*)(abase + ks * 32);
        fbuf[2 * ks + 1] = *(const float4*)(abase + ks * 32 + 4);
    }
    short8 afrag[4];
#pragma unroll
    for (int ks = 0; ks < 4; ++ks) {
        short8 t;
        t[0] = f2bf(fbuf[2 * ks].x);     t[1] = f2bf(fbuf[2 * ks].y);
        t[2] = f2bf(fbuf[2 * ks].z);     t[3] = f2bf(fbuf[2 * ks].w);
        t[4] = f2bf(fbuf[2 * ks + 1].x); t[5] = f2bf(fbuf[2 * ks + 1].y);
        t[6] = f2bf(fbuf[2 * ks + 1].z); t[7] = f2bf(fbuf[2 * ks + 1].w);
        afrag[ks] = t;
    }

    f32x4 acc[8][2];
#pragma unroll
    for (int nc = 0; nc < 8; ++nc)
#pragma unroll
        for (int s = 0; s < 2; ++s)
#pragma unroll
            for (int z = 0; z < 4; ++z) acc[nc][s][z] = 0.f;
    float e_acc[4] = {};

    __syncthreads();   // stage 0 + s_l/v_l ready

#pragma unroll
    for (int Q = 0; Q < 8; ++Q) {          // Q = h*4 + k-quarter
        const int hh = Q >> 2;
        const int qq = Q & 3;
#pragma unroll
        for (int st = 0; st < 4; ++st) {
            const int g = Q * 4 + st;      // global step, 0..31
            if (g < 31) {                  // stage pieces for step g+1
                const char* gs = (const char*)Whp + (size_t)(g + 1) * 16384;
                short* dst = lds_b[(g + 1) & 1];
#pragma unroll
                for (int j = 0; j < 4; ++j) {
                    int off = wave * 4096 + j * 1024;
                    GLOAD_LDS16(gs + off + lane * 16, (char*)dst + off);
                }
            }
            if (st == 1 && Q < 7) {        // prefetch next quarter's A (HBM)
                const float* ap = abase + ((Q + 1) & 3) * 128;
#pragma unroll
                for (int ks = 0; ks < 4; ++ks) {
                    fbuf[2 * ks]     = *(const float4*)(ap + ks * 32);
                    fbuf[2 * ks + 1] = *(const float4*)(ap + ks * 32 + 4);
                }
            }
#pragma unroll
            for (int pc = 0; pc < 2; ++pc) {
                const int nc = st * 2 + pc;
                const short* fp = lds_b[g & 1] + pc * 4096 + lane * 8;
#pragma unroll
                for (int s = 0; s < 2; ++s) {
#pragma unroll
                    for (int ks = 0; ks < 4; ++ks) {
                        short8 bf = *(const short8*)(fp + (s * 4 + ks) * 512);
                        acc[nc][s] = mfma16(afrag[ks], bf, acc[nc][s]);
                    }
                }
                if (qq == 3) {             // k complete for this half: finalize
#pragma unroll
                    for (int s = 0; s < 2; ++s) {
                        int n = hh * 256 + nc * 32 + s * 16 + lq;
                        float sv = s_l[n];
                        float vv = v_l[n];
#pragma unroll
                        for (int r = 0; r < 4; ++r)
                            e_acc[r] += tanh_fast(acc[nc][s][r] + sv) * vv;
#pragma unroll
                        for (int z = 0; z < 4; ++z) acc[nc][s][z] = 0.f;
                    }
                }
            }
            __syncthreads();   // buffer consumed; next stage complete
        }
        if (Q < 7) {           // convert prefetched A for next quarter
#pragma unroll
            for (int ks = 0; ks < 4; ++ks) {
                short8 t;
                t[0] = f2bf(fbuf[2 * ks].x);     t[1] = f2bf(fbuf[2 * ks].y);
                t[2] = f2bf(fbuf[2 * ks].z);     t[3] = f2bf(fbuf[2 * ks].w);
                t[4] = f2bf(fbuf[2 * ks + 1].x); t[5] = f2bf(fbuf[2 * ks + 1].y);
                t[6] = f2bf(fbuf[2 * ks + 1].z); t[7] = f2bf(fbuf[2 * ks + 1].w);
                afrag[ks] = t;
            }
        }
    }

    // e-reduction over 16 n-lanes -> masked e into LDS.
#pragma unroll
    for (int r = 0; r < 4; ++r) {
        float t = e_acc[r];
        t += __shfl_xor(t, 1, 16);
        t += __shfl_xor(t, 2, 16);
        t += __shfl_xor(t, 4, 16);
        t += __shfl_xor(t, 8, 16);
        if (lq == 0) {
            int mr = wave * 16 + q4 * 4 + r;
            e_l[mr] = mask[row0 + mr] ? t : NEGV;
        }
    }
    __syncthreads();

    // Local softmax partial (wave 0, one row per lane).
    if (wave == 0) {
        float x = e_l[lane];
        float m = x;
#pragma unroll
        for (int off = 32; off > 0; off >>= 1)
            m = fmaxf(m, __shfl_xor(m, off, 64));
        float p = __builtin_amdgcn_exp2f((x - m) * LOG2E);
        float sm = p;
#pragma unroll
        for (int off = 32; off > 0; off >>= 1)
            sm += __shfl_xor(sm, off, 64);
        e_l[lane] = p;
        if (lane == 0) {
            ml[blockIdx.x * 2]     = m;
            ml[blockIdx.x * 2 + 1] = sm;
        }
    }
    __syncthreads();

    // Partial context: each thread owns one float2 of H; enc tile is L2-hot.
    const float2* ep = (const float2*)(enc + (size_t)row0 * H_) + tid;
    float2 acc2 = {0.f, 0.f};
#pragma unroll 8
    for (int t = 0; t < 64; ++t) {
        float w = e_l[t];                 // LDS broadcast
        float2 v2 = ep[(size_t)t * 256];
        acc2.x += w * v2.x;
        acc2.y += w * v2.y;
    }
    ((float2*)(pctx + (size_t)blockIdx.x * 512))[tid] = acc2;
}

// ---------------------------------------------------------------------------
// Kernel 3: merge 64 block-partials per batch:
//   M = max_j m_j ; w_j = exp(m_j - M)
//   ctx[h] = sum_j w_j*pctx_j[h] / sum_j w_j*l_j
// grid (B), block 256.
__global__ __launch_bounds__(256) void combine_kernel(const float* __restrict__ pctx,
                                                      const float* __restrict__ ml,
                                                      float* __restrict__ out) {
    int b = blockIdx.x, tid = threadIdx.x;
    const float* mlb = ml + b * 128;   // 64 (m,l) pairs
    float M = -3.4e38f;
#pragma unroll
    for (int j = 0; j < 64; ++j) M = fmaxf(M, mlb[2 * j]);
    const float2* pc = (const float2*)(pctx + (size_t)b * 64 * 512) + tid;
    float denom = 0.f;
    float2 acc = {0.f, 0.f};
#pragma unroll
    for (int j = 0; j < 64; ++j) {
        float w = __builtin_amdgcn_exp2f((mlb[2 * j] - M) * LOG2E);
        denom += w * mlb[2 * j + 1];
        float2 p2 = pc[j * 256];
        acc.x += w * p2.x;
        acc.y += w * p2.y;
    }
    float inv = 1.0f / denom;
    float2 o;
    o.x = acc.x * inv;
    o.y = acc.y * inv;
    ((float2*)(out + b * H_))[tid] = o;
}

// ---------------------------------------------------------------------------
extern "C" void kernel_launch(void* const* d_in, const int* in_sizes, int n_in,
                              void* d_out, int out_size, void* d_ws, size_t ws_size,
                              hipStream_t stream) {
    (void)in_sizes; (void)n_in; (void)ws_size; (void)out_size;
    const float* enc  = (const float*)d_in[0];
    const int*   mask = (const int*)d_in[1];
    const float* dec  = (const float*)d_in[2];
    const float* Wh   = (const float*)d_in[3];
    const float* Ws   = (const float*)d_in[4];
    const float* v    = (const float*)d_in[5];
    float* out = (float*)d_out;

    short* whp_buf = (short*)d_ws;                       // 512 KiB
    float* s_buf   = (float*)(whp_buf + 512 * 512);      // 64 KiB
    float* pctx    = s_buf + B_ * H_;                    // 4 MiB (2048 x 512)
    float* ml      = pctx + 2048 * 512;                  // 16 KiB

    wh_prep<<<dim3(128), 256, 0, stream>>>(Wh, whp_buf);
    s_kernel<<<dim3(2, B_), 256, 0, stream>>>(dec, Ws, s_buf);
    e_fused<<<dim3(B_ * T_ / 64), 256, 0, stream>>>(enc, mask, whp_buf, s_buf, v,
                                                    pctx, ml);
    combine_kernel<<<dim3(B_), 256, 0, stream>>>(pctx, ml, out);
}